// Round 1
// baseline (619.608 us; speedup 1.0000x reference)
//
#include <hip/hip_runtime.h>

// MlpWithAttention: B=2^20 rows, in=64, H=32, out=64, fp32.
// Attention over T=1 sequence => softmax==1 => attn is affine: h <- h@(I+g*wv) + g*bv.
// Fold attn into preceding Linear on-device each call (preproc), then one
// fully-fused per-row kernel: GEMV(64x32) -> LN+leaky -> GEMV(32x32) -> LN+leaky -> GEMV(32x64).

#define HDIM 32
#define EPS 1e-5f
#define SLOPE 0.01f

// ws layout (floats):
//   0     .. 2048  : W1f[64][32]  (k-major, j contiguous)
//   2048  .. 2080  : B1f[32]
//   2080  .. 3104  : W2f[32][32]  (k-major)
//   3104  .. 3136  : B2f[32]
//   3136  .. 5184  : WoT[64][32]  (j-major, k contiguous)  WoT[j][k] = wo[k][j]
//   5184  .. 5248  : bo[64]

__global__ void mlp_preproc(
    const float* __restrict__ w1, const float* __restrict__ b1,
    const float* __restrict__ wv1, const float* __restrict__ bv1,
    const float* __restrict__ g1,
    const float* __restrict__ w2, const float* __restrict__ b2,
    const float* __restrict__ wv2, const float* __restrict__ bv2,
    const float* __restrict__ g2,
    const float* __restrict__ wo, const float* __restrict__ bo,
    float* __restrict__ ws)
{
    const int t = threadIdx.x;  // one block, 256 threads
    const float gg1 = g1[0], gg2 = g2[0];

    // W1f = w1 + g1*(w1@wv1)   [64x32]
    for (int e = t; e < 64 * HDIM; e += 256) {
        int k = e >> 5, j = e & 31;
        float acc = 0.f;
        for (int m = 0; m < HDIM; ++m) acc += w1[k * HDIM + m] * wv1[m * HDIM + j];
        ws[e] = w1[e] + gg1 * acc;
    }
    // B1f = b1 + g1*(b1@wv1 + bv1)
    if (t < HDIM) {
        int j = t;
        float s = 0.f;
        for (int m = 0; m < HDIM; ++m) s += b1[m] * wv1[m * HDIM + j];
        ws[2048 + j] = b1[j] + gg1 * (s + bv1[j]);
    }
    // W2f = w2 + g2*(w2@wv2)   [32x32]
    for (int e = t; e < HDIM * HDIM; e += 256) {
        int k = e >> 5, j = e & 31;
        float acc = 0.f;
        for (int m = 0; m < HDIM; ++m) acc += w2[k * HDIM + m] * wv2[m * HDIM + j];
        ws[2080 + e] = w2[e] + gg2 * acc;
    }
    // B2f
    if (t < HDIM) {
        int j = t;
        float s = 0.f;
        for (int m = 0; m < HDIM; ++m) s += b2[m] * wv2[m * HDIM + j];
        ws[3104 + j] = b2[j] + gg2 * (s + bv2[j]);
    }
    // WoT[j][k] = wo[k][j]   [64x32]
    for (int e = t; e < 64 * HDIM; e += 256) {
        int j = e >> 5, k = e & 31;
        ws[3136 + e] = wo[k * 64 + j];
    }
    // bo copy
    if (t < 64) ws[5184 + t] = bo[t];
}

__global__ __launch_bounds__(256, 4) void mlp_main(
    const float* __restrict__ x,
    const float* __restrict__ ws,
    const float* __restrict__ ln1g, const float* __restrict__ ln1b,
    const float* __restrict__ ln2g, const float* __restrict__ ln2b,
    float* __restrict__ out)
{
    const int row = blockIdx.x * 256 + threadIdx.x;

    const float* __restrict__ W1f = ws;
    const float* __restrict__ B1f = ws + 2048;
    const float* __restrict__ W2f = ws + 2080;
    const float* __restrict__ B2f = ws + 3104;
    const float* __restrict__ WoT = ws + 3136;
    const float* __restrict__ Bo  = ws + 5184;

    const float4* __restrict__ xr = (const float4*)(x + (size_t)row * 64);

    // ---------- GEMV1: h1 = x @ W1f + B1f  (K=64, uniform weights -> s_load) ----------
    float h1[HDIM];
#pragma unroll
    for (int j = 0; j < HDIM; ++j) h1[j] = B1f[j];

#pragma unroll 1
    for (int c = 0; c < 4; ++c) {           // rolled: 16 k's per iter
        alignas(16) float q[16];
        *(float4*)&q[0]  = xr[c * 4 + 0];
        *(float4*)&q[4]  = xr[c * 4 + 1];
        *(float4*)&q[8]  = xr[c * 4 + 2];
        *(float4*)&q[12] = xr[c * 4 + 3];
        const float* __restrict__ wb = W1f + c * 512;
#pragma unroll
        for (int kk = 0; kk < 16; ++kk) {
            const float xk = q[kk];
#pragma unroll
            for (int j = 0; j < HDIM; ++j)
                h1[j] = fmaf(xk, wb[kk * HDIM + j], h1[j]);
        }
    }

    // ---------- LN1 + leaky ----------
    {
        float m = 0.f;
#pragma unroll
        for (int j = 0; j < HDIM; ++j) m += h1[j];
        m *= (1.f / HDIM);
        float v = 0.f;
#pragma unroll
        for (int j = 0; j < HDIM; ++j) { float t = h1[j] - m; v = fmaf(t, t, v); }
        v *= (1.f / HDIM);
        const float rs = rsqrtf(v + EPS);
#pragma unroll
        for (int j = 0; j < HDIM; ++j) {
            float a = (h1[j] - m) * rs * ln1g[j] + ln1b[j];
            h1[j] = (a >= 0.f) ? a : SLOPE * a;
        }
    }

    // ---------- GEMV2: h2 = h1 @ W2f + B2f  (32x32, fully unrolled) ----------
    float h2[HDIM];
#pragma unroll
    for (int j = 0; j < HDIM; ++j) h2[j] = B2f[j];
#pragma unroll
    for (int k = 0; k < HDIM; ++k) {
        const float hk = h1[k];
#pragma unroll
        for (int j = 0; j < HDIM; ++j)
            h2[j] = fmaf(hk, W2f[k * HDIM + j], h2[j]);
    }

    // ---------- LN2 + leaky ----------
    {
        float m = 0.f;
#pragma unroll
        for (int j = 0; j < HDIM; ++j) m += h2[j];
        m *= (1.f / HDIM);
        float v = 0.f;
#pragma unroll
        for (int j = 0; j < HDIM; ++j) { float t = h2[j] - m; v = fmaf(t, t, v); }
        v *= (1.f / HDIM);
        const float rs = rsqrtf(v + EPS);
#pragma unroll
        for (int j = 0; j < HDIM; ++j) {
            float a = (h2[j] - m) * rs * ln2g[j] + ln2b[j];
            h2[j] = (a >= 0.f) ? a : SLOPE * a;
        }
    }

    // ---------- GEMV3: out = h2 @ wo + bo  (j chunks of 16, rolled) ----------
    float4* __restrict__ outr = (float4*)(out + (size_t)row * 64);
#pragma unroll 1
    for (int c = 0; c < 4; ++c) {
        float acc[16];
#pragma unroll
        for (int jj = 0; jj < 16; ++jj) acc[jj] = Bo[c * 16 + jj];
        const float* __restrict__ wb = WoT + c * 512;
#pragma unroll
        for (int jj = 0; jj < 16; ++jj) {
#pragma unroll
            for (int k = 0; k < HDIM; ++k)
                acc[jj] = fmaf(h2[k], wb[jj * HDIM + k], acc[jj]);
        }
        float4 o0 = { acc[0],  acc[1],  acc[2],  acc[3]  };
        float4 o1 = { acc[4],  acc[5],  acc[6],  acc[7]  };
        float4 o2 = { acc[8],  acc[9],  acc[10], acc[11] };
        float4 o3 = { acc[12], acc[13], acc[14], acc[15] };
        outr[c * 4 + 0] = o0;
        outr[c * 4 + 1] = o1;
        outr[c * 4 + 2] = o2;
        outr[c * 4 + 3] = o3;
    }
}

extern "C" void kernel_launch(void* const* d_in, const int* in_sizes, int n_in,
                              void* d_out, int out_size, void* d_ws, size_t ws_size,
                              hipStream_t stream) {
    const float* x    = (const float*)d_in[0];
    const float* w1   = (const float*)d_in[1];
    const float* b1   = (const float*)d_in[2];
    // d_in[3..6] = wq1,bq1,wk1,bk1 : dead (softmax over T=1 is identically 1)
    const float* wv1  = (const float*)d_in[7];
    const float* bv1  = (const float*)d_in[8];
    const float* g1   = (const float*)d_in[9];
    const float* ln1g = (const float*)d_in[10];
    const float* ln1b = (const float*)d_in[11];
    const float* w2   = (const float*)d_in[12];
    const float* b2   = (const float*)d_in[13];
    // d_in[14..17] dead
    const float* wv2  = (const float*)d_in[18];
    const float* bv2  = (const float*)d_in[19];
    const float* g2   = (const float*)d_in[20];
    const float* ln2g = (const float*)d_in[21];
    const float* ln2b = (const float*)d_in[22];
    const float* wo   = (const float*)d_in[23];
    const float* bo   = (const float*)d_in[24];

    float* ws = (float*)d_ws;
    float* out = (float*)d_out;

    const int rows = in_sizes[0] / 64;     // 1,048,576

    mlp_preproc<<<1, 256, 0, stream>>>(w1, b1, wv1, bv1, g1,
                                       w2, b2, wv2, bv2, g2,
                                       wo, bo, ws);

    mlp_main<<<rows / 256, 256, 0, stream>>>(x, ws, ln1g, ln1b, ln2g, ln2b, out);
}

// Round 2
// 613.046 us; speedup vs baseline: 1.0107x; 1.0107x over previous
//
#include <hip/hip_runtime.h>

// MlpWithAttention: B=2^20 rows, in=64, H=32, out=64, fp32.
// Attention over T=1 => softmax==1 => affine fold: h <- h@(I+g*wv) + g*bv,
// folded into the preceding Linear (preproc). Main kernel: one thread = one row,
// float2-packed math (v_pk_fma_f32) throughout, weights via wave-uniform s_load.

#define HDIM 32
#define EPS 1e-5f
#define SLOPE 0.01f

typedef float v2f __attribute__((ext_vector_type(2)));

// ws layout (floats):
//   0    .. 2048 : W1f[64][32]  (k-major, j contiguous)
//   2048 .. 2080 : B1f[32]
//   2080 .. 3104 : W2f[32][32]  (k-major)
//   3104 .. 3136 : B2f[32]

__global__ void mlp_preproc(
    const float* __restrict__ w1, const float* __restrict__ b1,
    const float* __restrict__ wv1, const float* __restrict__ bv1,
    const float* __restrict__ g1,
    const float* __restrict__ w2, const float* __restrict__ b2,
    const float* __restrict__ wv2, const float* __restrict__ bv2,
    const float* __restrict__ g2,
    float* __restrict__ ws)
{
    const int t = threadIdx.x;  // one block, 256 threads
    const float gg1 = g1[0], gg2 = g2[0];

    // W1f = w1 + g1*(w1@wv1)   [64x32]
    for (int e = t; e < 64 * HDIM; e += 256) {
        int k = e >> 5, j = e & 31;
        float acc = 0.f;
        for (int m = 0; m < HDIM; ++m) acc += w1[k * HDIM + m] * wv1[m * HDIM + j];
        ws[e] = w1[e] + gg1 * acc;
    }
    // B1f = b1 + g1*(b1@wv1 + bv1)
    if (t < HDIM) {
        int j = t;
        float s = 0.f;
        for (int m = 0; m < HDIM; ++m) s += b1[m] * wv1[m * HDIM + j];
        ws[2048 + j] = b1[j] + gg1 * (s + bv1[j]);
    }
    // W2f = w2 + g2*(w2@wv2)   [32x32]
    for (int e = t; e < HDIM * HDIM; e += 256) {
        int k = e >> 5, j = e & 31;
        float acc = 0.f;
        for (int m = 0; m < HDIM; ++m) acc += w2[k * HDIM + m] * wv2[m * HDIM + j];
        ws[2080 + e] = w2[e] + gg2 * acc;
    }
    // B2f
    if (t < HDIM) {
        int j = t;
        float s = 0.f;
        for (int m = 0; m < HDIM; ++m) s += b2[m] * wv2[m * HDIM + j];
        ws[3104 + j] = b2[j] + gg2 * (s + bv2[j]);
    }
}

__global__ __launch_bounds__(256)
__attribute__((amdgpu_waves_per_eu(4, 4)))
void mlp_main(
    const float* __restrict__ x,
    const float* __restrict__ ws,
    const float* __restrict__ ln1g, const float* __restrict__ ln1b,
    const float* __restrict__ ln2g, const float* __restrict__ ln2b,
    const float* __restrict__ wo,   const float* __restrict__ bo,
    float* __restrict__ out)
{
    const int row = blockIdx.x * 256 + threadIdx.x;

    const v2f* __restrict__ W1v = (const v2f*)ws;                // [64][16] v2f
    const v2f* __restrict__ B1v = (const v2f*)(ws + 2048);       // [16]
    const v2f* __restrict__ W2v = (const v2f*)(ws + 2080);       // [32][16]
    const v2f* __restrict__ B2v = (const v2f*)(ws + 3104);       // [16]
    const v2f* __restrict__ WoV = (const v2f*)wo;                // [32][32] v2f (k-major, 64 j's)
    const v2f* __restrict__ BoV = (const v2f*)bo;                // [32]
    const v2f* __restrict__ G1  = (const v2f*)ln1g;
    const v2f* __restrict__ Bt1 = (const v2f*)ln1b;
    const v2f* __restrict__ G2  = (const v2f*)ln2g;
    const v2f* __restrict__ Bt2 = (const v2f*)ln2b;

    const float4* __restrict__ xr = (const float4*)(x + (size_t)row * 64);

    // ---------- GEMV1: h1 = x @ W1f + B1f  (K=64) ----------
    v2f h1[16];
#pragma unroll
    for (int j = 0; j < 16; ++j) h1[j] = B1v[j];

#pragma unroll 1
    for (int c = 0; c < 4; ++c) {            // 16 k's per chunk
        alignas(16) float q[16];
        *(float4*)&q[0]  = xr[c * 4 + 0];
        *(float4*)&q[4]  = xr[c * 4 + 1];
        *(float4*)&q[8]  = xr[c * 4 + 2];
        *(float4*)&q[12] = xr[c * 4 + 3];
        const v2f* __restrict__ wb = W1v + c * 256;   // 16 k's x 16 v2f
#pragma unroll
        for (int kk = 0; kk < 16; ++kk) {
            const v2f xk2 = { q[kk], q[kk] };
#pragma unroll
            for (int j = 0; j < 16; ++j)
                h1[j] = h1[j] + xk2 * wb[kk * 16 + j];   // -> v_pk_fma_f32
        }
    }

    // ---------- LN1 + leaky ----------
    {
        v2f s = { 0.f, 0.f };
#pragma unroll
        for (int j = 0; j < 16; ++j) s = s + h1[j];
        const float m = (s.x + s.y) * (1.f / HDIM);
        const v2f mm = { m, m };
        v2f vs = { 0.f, 0.f };
#pragma unroll
        for (int j = 0; j < 16; ++j) { v2f t = h1[j] - mm; vs = vs + t * t; }
        const float rs = rsqrtf((vs.x + vs.y) * (1.f / HDIM) + EPS);
        const v2f rsv = { rs, rs };
#pragma unroll
        for (int j = 0; j < 16; ++j) {
            v2f a = (h1[j] - mm) * rsv * G1[j] + Bt1[j];
            a.x = fmaxf(a.x, SLOPE * a.x);
            a.y = fmaxf(a.y, SLOPE * a.y);
            h1[j] = a;
        }
    }

    // ---------- GEMV2: h2 = h1 @ W2f + B2f  (32x32) ----------
    v2f h2[16];
#pragma unroll
    for (int j = 0; j < 16; ++j) h2[j] = B2v[j];
#pragma unroll
    for (int i = 0; i < 16; ++i) {
        const v2f hx = { h1[i].x, h1[i].x };
        const v2f hy = { h1[i].y, h1[i].y };
        const v2f* __restrict__ w0 = W2v + (2 * i) * 16;
        const v2f* __restrict__ w1r = W2v + (2 * i + 1) * 16;
#pragma unroll
        for (int j = 0; j < 16; ++j) h2[j] = h2[j] + hx * w0[j];
#pragma unroll
        for (int j = 0; j < 16; ++j) h2[j] = h2[j] + hy * w1r[j];
    }

    // ---------- LN2 + leaky ----------
    {
        v2f s = { 0.f, 0.f };
#pragma unroll
        for (int j = 0; j < 16; ++j) s = s + h2[j];
        const float m = (s.x + s.y) * (1.f / HDIM);
        const v2f mm = { m, m };
        v2f vs = { 0.f, 0.f };
#pragma unroll
        for (int j = 0; j < 16; ++j) { v2f t = h2[j] - mm; vs = vs + t * t; }
        const float rs = rsqrtf((vs.x + vs.y) * (1.f / HDIM) + EPS);
        const v2f rsv = { rs, rs };
#pragma unroll
        for (int j = 0; j < 16; ++j) {
            v2f a = (h2[j] - mm) * rsv * G2[j] + Bt2[j];
            a.x = fmaxf(a.x, SLOPE * a.x);
            a.y = fmaxf(a.y, SLOPE * a.y);
            h2[j] = a;
        }
    }

    // ---------- GEMV3: out = h2 @ wo + bo  (K=32, N=64; j chunks of 16) ----------
    float4* __restrict__ outr = (float4*)(out + (size_t)row * 64);
#pragma unroll 1
    for (int c = 0; c < 4; ++c) {
        v2f acc[8];
#pragma unroll
        for (int j = 0; j < 8; ++j) acc[j] = BoV[c * 8 + j];
#pragma unroll
        for (int i = 0; i < 16; ++i) {
            const v2f hx = { h2[i].x, h2[i].x };
            const v2f hy = { h2[i].y, h2[i].y };
            const v2f* __restrict__ w0 = WoV + (2 * i) * 32 + c * 8;
            const v2f* __restrict__ w1r = WoV + (2 * i + 1) * 32 + c * 8;
#pragma unroll
            for (int j = 0; j < 8; ++j) acc[j] = acc[j] + hx * w0[j];
#pragma unroll
            for (int j = 0; j < 8; ++j) acc[j] = acc[j] + hy * w1r[j];
        }
        float4 o0 = { acc[0].x, acc[0].y, acc[1].x, acc[1].y };
        float4 o1 = { acc[2].x, acc[2].y, acc[3].x, acc[3].y };
        float4 o2 = { acc[4].x, acc[4].y, acc[5].x, acc[5].y };
        float4 o3 = { acc[6].x, acc[6].y, acc[7].x, acc[7].y };
        outr[c * 4 + 0] = o0;
        outr[c * 4 + 1] = o1;
        outr[c * 4 + 2] = o2;
        outr[c * 4 + 3] = o3;
    }
}

extern "C" void kernel_launch(void* const* d_in, const int* in_sizes, int n_in,
                              void* d_out, int out_size, void* d_ws, size_t ws_size,
                              hipStream_t stream) {
    const float* x    = (const float*)d_in[0];
    const float* w1   = (const float*)d_in[1];
    const float* b1   = (const float*)d_in[2];
    // d_in[3..6] = wq1,bq1,wk1,bk1 : dead (softmax over T=1 is identically 1)
    const float* wv1  = (const float*)d_in[7];
    const float* bv1  = (const float*)d_in[8];
    const float* g1   = (const float*)d_in[9];
    const float* ln1g = (const float*)d_in[10];
    const float* ln1b = (const float*)d_in[11];
    const float* w2   = (const float*)d_in[12];
    const float* b2   = (const float*)d_in[13];
    // d_in[14..17] dead
    const float* wv2  = (const float*)d_in[18];
    const float* bv2  = (const float*)d_in[19];
    const float* g2   = (const float*)d_in[20];
    const float* ln2g = (const float*)d_in[21];
    const float* ln2b = (const float*)d_in[22];
    const float* wo   = (const float*)d_in[23];
    const float* bo   = (const float*)d_in[24];

    float* ws = (float*)d_ws;
    float* out = (float*)d_out;

    const int rows = in_sizes[0] / 64;     // 1,048,576

    mlp_preproc<<<1, 256, 0, stream>>>(w1, b1, wv1, bv1, g1,
                                       w2, b2, wv2, bv2, g2, ws);

    mlp_main<<<rows / 256, 256, 0, stream>>>(x, ws, ln1g, ln1b, ln2g, ln2b,
                                             wo, bo, out);
}